// Round 3
// baseline (425.938 us; speedup 1.0000x reference)
//
#include <hip/hip_runtime.h>

#define N_TOK 4096
#define RD 64
#define CDIM 256

typedef __bf16 bf16x8 __attribute__((ext_vector_type(8)));
typedef float f32x4 __attribute__((ext_vector_type(4)));
typedef unsigned short u16;
typedef unsigned int u32;

__device__ __forceinline__ u16 f2bf(float f) {
  u32 u = __float_as_uint(f);
  u = (u + 0x7fffu + ((u >> 16) & 1u)) >> 16;  // RNE
  return (u16)u;
}

__device__ __forceinline__ f32x4 zero4() {
  f32x4 z = {0.f, 0.f, 0.f, 0.f};
  return z;
}

// ---------------------------------------------------------------------------
// Projection: out[n][o] = sum_c W[o][c] * X[b][c][n]   (1x1 conv as GEMM)
// form 1 (Q/K, O=64): out stored (n, 64) bf16.  A = Xt (n-rows), B = W.
// form 2 (V,  O=256): out stored (c, n)  bf16.  A = W (o-rows), B = Xt.
// LDS: Xt [64n][256c] bf16 @0 (32KB, 512B rows, XOR-swizzled)
//      Wc [64o][256c] bf16 @32768 (32KB, swizzled)
// ---------------------------------------------------------------------------
__global__ __launch_bounds__(256) void proj_kernel(
    const float* __restrict__ wli, const float* __restrict__ nbi,
    const float* __restrict__ wq0, const float* __restrict__ wk0,
    const float* __restrict__ wv0, const float* __restrict__ wq1,
    const float* __restrict__ wk1, const float* __restrict__ wv1,
    u16* __restrict__ Qb, u16* __restrict__ Kb, u16* __restrict__ Vb) {
  extern __shared__ char smem[];
  const int ntile = blockIdx.x, bb = blockIdx.y, pid = blockIdx.z;
  const int tid = threadIdx.x;
  const int w = tid >> 6, lane = tid & 63, g = lane >> 4, l15 = lane & 15;
  const int n0 = ntile * 64;

  const float* X;
  const float* W;
  u16* out;
  float scale = 1.f;
  int form, nchunk;
  switch (pid) {
    case 0: X = wli; W = wq0; out = Qb + (size_t)(0 + bb) * N_TOK * RD; scale = 0.125f; form = 1; nchunk = 1; break;
    case 1: X = nbi; W = wk0; out = Kb + (size_t)(0 + bb) * N_TOK * RD; form = 1; nchunk = 1; break;
    case 2: X = nbi; W = wv0; out = Vb + (size_t)(0 + bb) * CDIM * N_TOK; form = 2; nchunk = 4; break;
    case 3: X = nbi; W = wq1; out = Qb + (size_t)(4 + bb) * N_TOK * RD; scale = 0.125f; form = 1; nchunk = 1; break;
    case 4: X = wli; W = wk1; out = Kb + (size_t)(4 + bb) * N_TOK * RD; form = 1; nchunk = 1; break;
    default: X = wli; W = wv1; out = Vb + (size_t)(4 + bb) * CDIM * N_TOK; form = 2; nchunk = 4; break;
  }
  X += (size_t)bb * CDIM * N_TOK;

  // stage Xt: transpose (c,n)->(n,c), f32->bf16, fold scale
#pragma unroll
  for (int rep = 0; rep < 16; ++rep) {
    int idx = rep * 256 + tid;
    int c = idx >> 4;
    int nq = (idx & 15) * 4;
    float4 v = *(const float4*)(X + (size_t)c * N_TOK + n0 + nq);
    float vv[4] = {v.x, v.y, v.z, v.w};
#pragma unroll
    for (int k = 0; k < 4; ++k) {
      int row = nq + k;
      int addr = (row * 512 + c * 2) ^ ((row & 7) << 4);
      *(u16*)(smem + addr) = f2bf(vv[k] * scale);
    }
  }

  for (int oc = 0; oc < nchunk; ++oc) {
    // stage W chunk (64 o-rows x 256 c)
#pragma unroll
    for (int rep = 0; rep < 16; ++rep) {
      int idx = rep * 256 + tid;
      int o = idx >> 6;
      int c4 = (idx & 63) * 4;
      float4 v = *(const float4*)(W + (size_t)(oc * 64 + o) * CDIM + c4);
      ushort4 pk = {f2bf(v.x), f2bf(v.y), f2bf(v.z), f2bf(v.w)};
      int addr = 32768 + ((o * 512 + c4 * 2) ^ ((o & 7) << 4));
      *(ushort4*)(smem + addr) = pk;
    }
    __syncthreads();

    f32x4 acc[4];
#pragma unroll
    for (int ct = 0; ct < 4; ++ct) acc[ct] = zero4();
    const int arow = w * 16 + l15;
    const int abase = (form == 1) ? 0 : 32768;
    const int bbase = (form == 1) ? 32768 : 0;
#pragma unroll
    for (int kk = 0; kk < 8; ++kk) {
      int koff = kk * 64 + g * 16;  // byte offset of k=(kk*32 + g*8)
      bf16x8 af = *(const bf16x8*)(smem + abase + ((arow * 512 + koff) ^ ((arow & 7) << 4)));
#pragma unroll
      for (int ct = 0; ct < 4; ++ct) {
        int brow = ct * 16 + l15;
        bf16x8 bfr = *(const bf16x8*)(smem + bbase + ((brow * 512 + koff) ^ ((brow & 7) << 4)));
        acc[ct] = __builtin_amdgcn_mfma_f32_16x16x32_bf16(af, bfr, acc[ct], 0, 0, 0);
      }
    }
    if (form == 1) {
      // D: col = o = ct*16+l15, row = n_local = g*4+r
#pragma unroll
      for (int ct = 0; ct < 4; ++ct)
#pragma unroll
        for (int r = 0; r < 4; ++r)
          out[(size_t)(n0 + w * 16 + g * 4 + r) * RD + ct * 16 + l15] = f2bf(acc[ct][r]);
    } else {
      // D: col = n = ct*16+l15, row = o_local = g*4+r ; out is (c, n)
#pragma unroll
      for (int ct = 0; ct < 4; ++ct)
#pragma unroll
        for (int r = 0; r < 4; ++r)
          out[(size_t)(oc * 64 + w * 16 + g * 4 + r) * N_TOK + n0 + ct * 16 + l15] = f2bf(acc[ct][r]);
    }
    __syncthreads();
  }
}

// ---------------------------------------------------------------------------
// Flash attention + residual.  Per block: 64 q-rows (4 waves x 16), stream 64
// KV tiles of 64.  Swapped QK^T (mfma(K,Q)) -> lane owns q-row l15.
// LDS: K [64j][64r] @0 (8KB) | Vt [256c][64j] @8192 (32KB) | P @40960 (8KB)
// all XOR-swizzled: byte ^= (row&7)<<4
// ---------------------------------------------------------------------------
__global__ __launch_bounds__(256) void attn_kernel(
    const u16* __restrict__ Qb, const u16* __restrict__ Kb,
    const u16* __restrict__ Vb, const float* __restrict__ x_wli,
    const float* __restrict__ x_nbi, float* __restrict__ y) {
  extern __shared__ char smem[];
  const int ntile = blockIdx.x, bb = blockIdx.y, br = blockIdx.z;
  const int tid = threadIdx.x;
  const int w = tid >> 6, lane = tid & 63, g = lane >> 4, l15 = lane & 15;
  const int inst = br * 4 + bb;
  const u16* Q = Qb + (size_t)inst * N_TOK * RD + (size_t)ntile * 64 * RD;
  const u16* K = Kb + (size_t)inst * N_TOK * RD;
  const u16* Vt = Vb + (size_t)inst * CDIM * N_TOK;
  const float* xres = (br == 0 ? x_wli : x_nbi) + (size_t)bb * CDIM * N_TOK;
  float* yout = y + (size_t)inst * CDIM * N_TOK;

  // Q fragments held in registers for the whole kernel (B-operand of S^T)
  bf16x8 qf[2];
  {
    const u16* qrow = Q + (w * 16 + l15) * RD;
    qf[0] = *(const bf16x8*)(qrow + g * 8);
    qf[1] = *(const bf16x8*)(qrow + 32 + g * 8);
  }
  f32x4 o_acc[16];
#pragma unroll
  for (int i = 0; i < 16; ++i) o_acc[i] = zero4();
  float m_ln = -1e30f, l_ln = 0.f;
  const float LOG2E = 1.44269504088896340736f;

  for (int t = 0; t < 64; ++t) {
    const int kv0 = t * 64;
    // stage K tile (8KB): 512 x 16B chunks
#pragma unroll
    for (int rep = 0; rep < 2; ++rep) {
      int id = rep * 256 + tid;
      int j = id >> 3, off = (id & 7) * 8;
      float4 v = *(const float4*)(K + (size_t)(kv0 + j) * RD + off);
      int addr = (j * 128 + off * 2) ^ ((j & 7) << 4);
      *(float4*)(smem + addr) = v;
    }
    // stage V tile (32KB): 2048 x 16B chunks
#pragma unroll
    for (int rep = 0; rep < 8; ++rep) {
      int id = rep * 256 + tid;
      int c = id >> 3, off = (id & 7) * 8;
      float4 v = *(const float4*)(Vt + (size_t)c * N_TOK + kv0 + off);
      int addr = 8192 + ((c * 128 + off * 2) ^ ((c & 7) << 4));
      *(float4*)(smem + addr) = v;
    }
    __syncthreads();

    // S^T = K . Q^T : D col = q-row (l15), D row = kv j (g*4+r within jt*16)
    f32x4 s[4];
#pragma unroll
    for (int jt = 0; jt < 4; ++jt) {
      f32x4 acc = zero4();
#pragma unroll
      for (int kk = 0; kk < 2; ++kk) {
        int row = jt * 16 + l15;
        int addr = (row * 128 + kk * 64 + g * 16) ^ ((row & 7) << 4);
        bf16x8 kf = *(const bf16x8*)(smem + addr);
        acc = __builtin_amdgcn_mfma_f32_16x16x32_bf16(kf, qf[kk], acc, 0, 0, 0);
      }
      s[jt] = acc;
    }

    // online softmax, lane owns q-row l15 (replicated across g)
    float mx = s[0][0];
#pragma unroll
    for (int jt = 0; jt < 4; ++jt)
#pragma unroll
      for (int r = 0; r < 4; ++r) mx = fmaxf(mx, s[jt][r]);
    mx = fmaxf(mx, __shfl_xor(mx, 16));
    mx = fmaxf(mx, __shfl_xor(mx, 32));
    float mnew = fmaxf(m_ln, mx);
    float corr = exp2f((m_ln - mnew) * LOG2E);
    m_ln = mnew;
    float sum = 0.f;
#pragma unroll
    for (int jt = 0; jt < 4; ++jt)
#pragma unroll
      for (int r = 0; r < 4; ++r) {
        float p = exp2f((s[jt][r] - mnew) * LOG2E);
        s[jt][r] = p;
        sum += p;
      }
    sum += __shfl_xor(sum, 16);
    sum += __shfl_xor(sum, 32);
    l_ln = l_ln * corr + sum;

    // write P^T -> P_lds[i=l15][j], per-wave region (no cross-wave sharing)
#pragma unroll
    for (int jt = 0; jt < 4; ++jt)
#pragma unroll
      for (int r = 0; r < 4; ++r) {
        int jcol = jt * 16 + g * 4 + r;
        int addr = 40960 + w * 2048 + ((l15 * 128 + jcol * 2) ^ ((l15 & 7) << 4));
        *(u16*)(smem + addr) = f2bf(s[jt][r]);
      }

    // rescale O; O rows are g*4+r -> fetch that row's corr via shfl
    float corrO[4];
#pragma unroll
    for (int r = 0; r < 4; ++r) corrO[r] = __shfl(corr, (lane & 48) | (g * 4 + r));
#pragma unroll
    for (int ct = 0; ct < 16; ++ct)
#pragma unroll
      for (int r = 0; r < 4; ++r) o_acc[ct][r] *= corrO[r];

    __threadfence_block();  // order P writes before P fragment reads

    bf16x8 pf[2];
#pragma unroll
    for (int kk = 0; kk < 2; ++kk) {
      int addr = 40960 + w * 2048 + ((l15 * 128 + kk * 64 + g * 16) ^ ((l15 & 7) << 4));
      pf[kk] = *(const bf16x8*)(smem + addr);
    }
    // PV: O[i][c] += P[i][j] V[j][c];  B from Vt (c-rows)
#pragma unroll
    for (int ct = 0; ct < 16; ++ct) {
#pragma unroll
      for (int kk = 0; kk < 2; ++kk) {
        int c = ct * 16 + l15;
        int addr = 8192 + ((c * 128 + kk * 64 + g * 16) ^ ((c & 7) << 4));
        bf16x8 vf = *(const bf16x8*)(smem + addr);
        o_acc[ct] = __builtin_amdgcn_mfma_f32_16x16x32_bf16(pf[kk], vf, o_acc[ct], 0, 0, 0);
      }
    }
    __syncthreads();  // all waves done with K/V before next stage
  }

  // epilogue: y = x + O/l   (y layout (br,b,c,n))
  float rl = 1.f / l_ln;
  float rlO[4];
#pragma unroll
  for (int r = 0; r < 4; ++r) rlO[r] = __shfl(rl, (lane & 48) | (g * 4 + r));
  const int nbase = ntile * 64 + w * 16;
#pragma unroll
  for (int ct = 0; ct < 16; ++ct) {
    int c = ct * 16 + l15;
#pragma unroll
    for (int r = 0; r < 4; ++r) {
      size_t idx = (size_t)c * N_TOK + nbase + g * 4 + r;
      yout[idx] = xres[idx] + o_acc[ct][r] * rlO[r];
    }
  }
}

// ---------------------------------------------------------------------------
// BN stats: one block per (branch, channel); mean + rsqrt(var+eps) over 16384
// ---------------------------------------------------------------------------
__global__ __launch_bounds__(256) void bn_stats_kernel(const float* __restrict__ y,
                                                       float* __restrict__ stats) {
  const int idx = blockIdx.x;  // branch*256 + c
  const int br = idx >> 8, c = idx & 255;
  const float* base = y + (size_t)br * 4 * CDIM * N_TOK + (size_t)c * N_TOK;
  float s1 = 0.f, s2 = 0.f;
#pragma unroll
  for (int bb = 0; bb < 4; ++bb) {
    const float* p = base + (size_t)bb * CDIM * N_TOK;
    for (int off = threadIdx.x * 4; off < N_TOK; off += 1024) {
      float4 v = *(const float4*)(p + off);
      s1 += v.x + v.y + v.z + v.w;
      s2 += v.x * v.x + v.y * v.y + v.z * v.z + v.w * v.w;
    }
  }
#pragma unroll
  for (int msk = 1; msk < 64; msk <<= 1) {
    s1 += __shfl_xor(s1, msk);
    s2 += __shfl_xor(s2, msk);
  }
  __shared__ float a1[4], a2[4];
  const int wv = threadIdx.x >> 6, ln = threadIdx.x & 63;
  if (ln == 0) { a1[wv] = s1; a2[wv] = s2; }
  __syncthreads();
  if (threadIdx.x == 0) {
    float t1 = a1[0] + a1[1] + a1[2] + a1[3];
    float t2 = a2[0] + a2[1] + a2[2] + a2[3];
    float mean = t1 * (1.f / 16384.f);
    float var = t2 * (1.f / 16384.f) - mean * mean;
    stats[idx] = mean;
    stats[512 + idx] = rsqrtf(var + 1e-5f);
  }
}

__global__ __launch_bounds__(256) void bn_apply_kernel(
    const float* __restrict__ y, const float* __restrict__ stats,
    const float* __restrict__ g0, const float* __restrict__ b0,
    const float* __restrict__ g1, const float* __restrict__ b1,
    float* __restrict__ out) {
  size_t i4 = (size_t)blockIdx.x * 256 + threadIdx.x;  // 2M float4s
  int br = (int)(i4 >> 20);
  int c = (int)(i4 >> 10) & 255;
  float mean = stats[br * 256 + c];
  float rstd = stats[512 + br * 256 + c];
  float ga = (br ? g1 : g0)[c];
  float be = (br ? b1 : b0)[c];
  float a = rstd * ga;
  float4 v = *(const float4*)(y + i4 * 4);
  v.x = (v.x - mean) * a + be;
  v.y = (v.y - mean) * a + be;
  v.z = (v.z - mean) * a + be;
  v.w = (v.w - mean) * a + be;
  *(float4*)(out + i4 * 4) = v;
}

// ---------------------------------------------------------------------------
extern "C" void kernel_launch(void* const* d_in, const int* in_sizes, int n_in,
                              void* d_out, int out_size, void* d_ws, size_t ws_size,
                              hipStream_t stream) {
  const float* wli = (const float*)d_in[0];
  const float* nbi = (const float*)d_in[1];
  const float* wq0 = (const float*)d_in[2];
  const float* wk0 = (const float*)d_in[3];
  const float* wv0 = (const float*)d_in[4];
  const float* wq1 = (const float*)d_in[5];
  const float* wk1 = (const float*)d_in[6];
  const float* wv1 = (const float*)d_in[7];
  const float* g0 = (const float*)d_in[8];
  const float* b0 = (const float*)d_in[9];
  const float* g1 = (const float*)d_in[10];
  const float* b1 = (const float*)d_in[11];

  char* ws = (char*)d_ws;
  // bf16 Q: 2*4*4096*64 = 2M elems (4MB); K same; V: 2*4*256*4096 (16MB)
  u16* Qb = (u16*)(ws + 0);
  u16* Kb = (u16*)(ws + 4194304);
  u16* Vb = (u16*)(ws + 8388608);
  float* y = (float*)(ws + 25165824);     // 2*4*256*4096 f32 (32MB)
  float* stats = (float*)(ws + 58720256); // 512 means + 512 rstds

  proj_kernel<<<dim3(64, 4, 6), 256, 65536, stream>>>(wli, nbi, wq0, wk0, wv0,
                                                      wq1, wk1, wv1, Qb, Kb, Vb);
  attn_kernel<<<dim3(64, 4, 2), 256, 49152, stream>>>(Qb, Kb, Vb, wli, nbi, y);
  bn_stats_kernel<<<dim3(512), 256, 0, stream>>>(y, stats);
  bn_apply_kernel<<<dim3(8192), 256, 0, stream>>>(y, stats, g0, b0, g1, b1,
                                                  (float*)d_out);
}